// Round 6
// baseline (602.919 us; speedup 1.0000x reference)
//
#include <hip/hip_runtime.h>

// ---------- types / helpers ----------
typedef __attribute__((ext_vector_type(8))) short short8;   // 8 x bf16 (4 VGPR)
typedef __attribute__((ext_vector_type(4))) float f32x4;    // MFMA acc

__device__ __forceinline__ unsigned short f2b(float f) {
  union { float f; unsigned u; } v; v.f = f;
  unsigned r = v.u + 0x7fffu + ((v.u >> 16) & 1u);   // RNE bf16
  return (unsigned short)(r >> 16);
}
__device__ __forceinline__ float b2f(unsigned short b) {
  union { unsigned u; float f; } v; v.u = ((unsigned)b) << 16; return v.f;
}

// async global->LDS, 16B per lane; lds dest = wave-uniform base + lane*16
__device__ __forceinline__ void gload_lds16(const void* g, void* l) {
  __builtin_amdgcn_global_load_lds(
      (const __attribute__((address_space(1))) void*)g,
      (__attribute__((address_space(3))) void*)l, 16, 0, 0);
}

// ---------- fp32 -> bf16 weight convert ----------
__global__ __launch_bounds__(256) void cvt_k(const float* __restrict__ s,
                                             unsigned short* __restrict__ d, int n4) {
  int i = blockIdx.x * 256 + threadIdx.x;
  if (i >= n4) return;
  float4 v = ((const float4*)s)[i];
  ushort4 o;
  o.x = f2b(v.x); o.y = f2b(v.y); o.z = f2b(v.z); o.w = f2b(v.w);
  ((ushort4*)d)[i] = o;
}

// ---------- RMSNorm (fp32 in -> bf16 out), one row per block ----------
__global__ __launch_bounds__(256) void rmsnorm_k(const float* __restrict__ x,
                                                 const float* __restrict__ g,
                                                 unsigned short* __restrict__ out) {
  const int row = blockIdx.x, tid = threadIdx.x;
  const float4 v = ((const float4*)(x + (size_t)row * 1024))[tid];
  float ss = v.x*v.x + v.y*v.y + v.z*v.z + v.w*v.w;
  #pragma unroll
  for (int d = 32; d > 0; d >>= 1) ss += __shfl_down(ss, d);
  __shared__ float red[4];
  if ((tid & 63) == 0) red[tid >> 6] = ss;
  __syncthreads();
  const float tot = red[0] + red[1] + red[2] + red[3];
  const float sc = rsqrtf(tot * (1.0f/1024.0f) + 1e-5f);
  const float4 gg = ((const float4*)g)[tid];
  ushort4 o;
  o.x = f2b(v.x * sc * gg.x); o.y = f2b(v.y * sc * gg.y);
  o.z = f2b(v.z * sc * gg.z); o.w = f2b(v.w * sc * gg.w);
  ((ushort4*)(out + (size_t)row * 1024))[tid] = o;
}

// ---------- SwiGLU gate: p1 <- silu(p1)*p3 ----------
__global__ __launch_bounds__(256) void gate_k(unsigned short* __restrict__ p13) {
  const size_t i = (size_t)blockIdx.x * 256 + threadIdx.x;
  const int r = (int)(i >> 9);
  const int fc = ((int)i & 511) * 8;
  unsigned short* p1 = p13 + (size_t)r * 8192 + fc;
  const unsigned short* p3 = p13 + (size_t)r * 8192 + 4096 + fc;
  ushort4 a0 = ((const ushort4*)p1)[0], a1 = ((const ushort4*)p1)[1];
  ushort4 b0 = ((const ushort4*)p3)[0], b1 = ((const ushort4*)p3)[1];
  unsigned short va[8] = {a0.x,a0.y,a0.z,a0.w,a1.x,a1.y,a1.z,a1.w};
  unsigned short vb[8] = {b0.x,b0.y,b0.z,b0.w,b1.x,b1.y,b1.z,b1.w};
  unsigned short vo[8];
  #pragma unroll
  for (int j = 0; j < 8; ++j) {
    float f1 = b2f(va[j]), f3 = b2f(vb[j]);
    float s = f1 / (1.0f + __expf(-f1));
    vo[j] = f2b(s * f3);
  }
  ushort4 o0 = {vo[0],vo[1],vo[2],vo[3]}, o1 = {vo[4],vo[5],vo[6],vo[7]};
  ((ushort4*)p1)[0] = o0; ((ushort4*)p1)[1] = o1;
}

// ---------- 128-tile GEMM (proven m97 structure): C = A * W^T ----------
template<int EPI>
__global__ __launch_bounds__(256) void gemm_bt(
    const unsigned short* __restrict__ A, const unsigned short* __restrict__ W,
    int N, int K, int lda,
    unsigned short* __restrict__ Cb, const float* __restrict__ res,
    float* __restrict__ Cf, int ldc)
{
  __shared__ unsigned short sA[4096];   // [128][32]
  __shared__ unsigned short sB[4096];   // [128][32]
  const int tid = threadIdx.x;
  const int w = tid >> 6, l = tid & 63;
  const int l15 = l & 15, l4 = l >> 4;
  const int bm = blockIdx.y * 128, bn = blockIdx.x * 128;
  const int wm = (w >> 1) * 64, wn = (w & 1) * 64;
  const int c0 = w * 128 + l;
  const int ra0 = c0 >> 2,        ka0 = (c0 & 3) * 8;
  const int ra1 = (c0 + 64) >> 2, ka1 = ((c0 + 64) & 3) * 8;
  const unsigned short* Ar0 = A + (size_t)(bm + ra0) * lda + ka0;
  const unsigned short* Ar1 = A + (size_t)(bm + ra1) * lda + ka1;
  const unsigned short* Wr0 = W + (size_t)(bn + ra0) * K + ka0;
  const unsigned short* Wr1 = W + (size_t)(bn + ra1) * K + ka1;
  f32x4 acc[4][4];
  const f32x4 z4 = {0.f, 0.f, 0.f, 0.f};
  #pragma unroll
  for (int i = 0; i < 4; ++i)
    #pragma unroll
    for (int j = 0; j < 4; ++j) acc[i][j] = z4;

  for (int kt = 0; kt < K; kt += 32) {
    gload_lds16(Ar0 + kt, &sA[w * 1024]);
    gload_lds16(Ar1 + kt, &sA[w * 1024 + 512]);
    gload_lds16(Wr0 + kt, &sB[w * 1024]);
    gload_lds16(Wr1 + kt, &sB[w * 1024 + 512]);
    __syncthreads();
    short8 af[4], bf[4];
    #pragma unroll
    for (int mi = 0; mi < 4; ++mi)
      af[mi] = *(const short8*)&sA[(wm + mi*16 + l15)*32 + l4*8];
    #pragma unroll
    for (int ni = 0; ni < 4; ++ni)
      bf[ni] = *(const short8*)&sB[(wn + ni*16 + l15)*32 + l4*8];
    #pragma unroll
    for (int mi = 0; mi < 4; ++mi)
      #pragma unroll
      for (int ni = 0; ni < 4; ++ni)
        acc[mi][ni] = __builtin_amdgcn_mfma_f32_16x16x32_bf16(af[mi], bf[ni], acc[mi][ni], 0, 0, 0);
    __syncthreads();
  }
  #pragma unroll
  for (int mi = 0; mi < 4; ++mi)
    #pragma unroll
    for (int ni = 0; ni < 4; ++ni) {
      const int row0 = bm + wm + mi*16 + l4*4;
      const int col  = bn + wn + ni*16 + l15;
      #pragma unroll
      for (int r = 0; r < 4; ++r) {
        const float v = acc[mi][ni][r];
        if (EPI == 0) {
          Cb[(size_t)(row0 + r) * ldc + col] = f2b(v);
        } else {
          const size_t o = (size_t)(row0 + r) * ldc + col;
          Cf[o] = res[o] + v;
        }
      }
    }
}

// ---------- 256-tile pipelined GEMM: C[M,N] = A[M,K] * W[N,K]^T, bf16 out ----------
__global__ __launch_bounds__(512, 2) void gemm256_bt(
    const unsigned short* __restrict__ A, const unsigned short* __restrict__ W,
    int K, int lda, unsigned short* __restrict__ Cb, int ldc, int nbx)
{
  __shared__ unsigned short sA[4][8192];   // per buf: 16 subtiles of 16x32
  __shared__ unsigned short sB[4][8192];
  const int tid = threadIdx.x;
  const int w = tid >> 6, l = tid & 63;
  const int l15 = l & 15, l4 = l >> 4;
  const int nwg = nbx * gridDim.y;
  const int flat = blockIdx.y * nbx + blockIdx.x;
  const int q8 = nwg >> 3;
  const int sw = (flat & 7) * q8 + (flat >> 3);
  const int bm = (sw / nbx) * 256, bn = (sw % nbx) * 256;

  int rowl[2], coll[2];
  #pragma unroll
  for (int i = 0; i < 2; ++i) {
    const int g = w * 128 + i * 64 + l;
    const int s = g >> 6, j = g & 63;
    const int r = j >> 2, c8 = (j & 3) * 8;
    rowl[i] = s * 16 + r;
    coll[i] = c8 ^ ((r & 8) << 1);
  }
  const unsigned short* As0 = A + (size_t)(bm + rowl[0]) * lda + coll[0];
  const unsigned short* As1 = A + (size_t)(bm + rowl[1]) * lda + coll[1];
  const unsigned short* Ws0 = W + (size_t)(bn + rowl[0]) * K + coll[0];
  const unsigned short* Ws1 = W + (size_t)(bn + rowl[1]) * K + coll[1];
  const int d0 = w * 1024, d1 = w * 1024 + 512;

  const int swzr = (l4 * 8) ^ ((l15 & 8) << 1);
  const int aoff = (w >> 2) * 4096 + l15 * 32 + swzr;
  const int boff = (w & 3) * 2048 + l15 * 32 + swzr;

  f32x4 acc[8][4];
  const f32x4 z4 = {0.f, 0.f, 0.f, 0.f};
  #pragma unroll
  for (int i = 0; i < 8; ++i)
    #pragma unroll
    for (int j = 0; j < 4; ++j) acc[i][j] = z4;

  const int NT = K >> 5;
  #pragma unroll
  for (int p = 0; p < 3; ++p) {
    const int ko = p * 32;
    gload_lds16(As0 + ko, &sA[p][d0]);
    gload_lds16(As1 + ko, &sA[p][d1]);
    gload_lds16(Ws0 + ko, &sB[p][d0]);
    gload_lds16(Ws1 + ko, &sB[p][d1]);
  }
  asm volatile("s_waitcnt vmcnt(8)" ::: "memory");
  __builtin_amdgcn_s_barrier();

  for (int t = 0; t < NT; ++t) {
    const unsigned short* a_ = sA[t & 3];
    const unsigned short* b_ = sB[t & 3];
    const bool st = (t + 3 < NT);
    const int nb = (t + 3) & 3;
    const int ko = (t + 3) * 32;
    short8 bfr[4], afr[4];
    #pragma unroll
    for (int ni = 0; ni < 4; ++ni) bfr[ni] = *(const short8*)&b_[boff + ni * 512];
    #pragma unroll
    for (int mi = 0; mi < 4; ++mi) afr[mi] = *(const short8*)&a_[aoff + mi * 512];
    if (st) { gload_lds16(As0 + ko, &sA[nb][d0]); gload_lds16(Ws0 + ko, &sB[nb][d0]); }
    __builtin_amdgcn_s_barrier();
    asm volatile("s_waitcnt lgkmcnt(0)" ::: "memory");
    __builtin_amdgcn_sched_barrier(0);
    __builtin_amdgcn_s_setprio(1);
    #pragma unroll
    for (int mi = 0; mi < 4; ++mi)
      #pragma unroll
      for (int ni = 0; ni < 4; ++ni)
        acc[mi][ni] = __builtin_amdgcn_mfma_f32_16x16x32_bf16(bfr[ni], afr[mi], acc[mi][ni], 0, 0, 0);
    __builtin_amdgcn_s_setprio(0);
    __builtin_amdgcn_s_barrier();
    #pragma unroll
    for (int mi = 0; mi < 4; ++mi) afr[mi] = *(const short8*)&a_[aoff + (mi + 4) * 512];
    if (st) { gload_lds16(As1 + ko, &sA[nb][d1]); gload_lds16(Ws1 + ko, &sB[nb][d1]); }
    __builtin_amdgcn_s_barrier();
    asm volatile("s_waitcnt lgkmcnt(0)" ::: "memory");
    __builtin_amdgcn_sched_barrier(0);
    __builtin_amdgcn_s_setprio(1);
    #pragma unroll
    for (int mi = 0; mi < 4; ++mi)
      #pragma unroll
      for (int ni = 0; ni < 4; ++ni)
        acc[mi + 4][ni] = __builtin_amdgcn_mfma_f32_16x16x32_bf16(bfr[ni], afr[mi], acc[mi + 4][ni], 0, 0, 0);
    __builtin_amdgcn_s_setprio(0);
    if (t < NT - 3)       asm volatile("s_waitcnt vmcnt(8)" ::: "memory");
    else if (t == NT - 3) asm volatile("s_waitcnt vmcnt(4)" ::: "memory");
    else                  asm volatile("s_waitcnt vmcnt(0)" ::: "memory");
    __builtin_amdgcn_s_barrier();
  }
  #pragma unroll
  for (int mi = 0; mi < 8; ++mi) {
    const int row = bm + (w >> 2) * 128 + mi * 16 + l15;
    #pragma unroll
    for (int ni = 0; ni < 4; ++ni) {
      const int col = bn + (w & 3) * 64 + ni * 16 + l4 * 4;
      ushort4 o = { f2b(acc[mi][ni][0]), f2b(acc[mi][ni][1]),
                    f2b(acc[mi][ni][2]), f2b(acc[mi][ni][3]) };
      *(ushort4*)&Cb[(size_t)row * ldc + col] = o;
    }
  }
}

// ---------- V transpose: VT[b][d][s] <- QKV v-part [b][s][d] ----------
__global__ __launch_bounds__(256) void vtrans_k(const unsigned short* __restrict__ QKV,
                                                unsigned short* __restrict__ VT) {
  __shared__ unsigned short sT[4096];  // [64 s][64 d], chunk-swizzled
  const int st = blockIdx.x, dt = blockIdx.y, b = blockIdx.z;
  const int tid = threadIdx.x;
  #pragma unroll
  for (int half = 0; half < 2; ++half) {
    const int c = tid + half * 256;
    const int r = c >> 3;              // s-local row
    const int ch = c & 7;              // d-chunk
    const unsigned short* src =
        QKV + (size_t)(b*2048 + st*64 + r) * 3072 + 2048 + dt*64 + ch*8;
    short8 v = *(const short8*)src;
    *(short8*)&sT[r*64 + ((ch ^ ((r >> 3) & 7)) * 8)] = v;
  }
  __syncthreads();
  #pragma unroll
  for (int half = 0; half < 2; ++half) {
    const int c = tid + half * 256;
    const int od = c >> 3;             // d-local row of VT
    const int oc = c & 7;              // s-chunk
    unsigned short tmp[8];
    #pragma unroll
    for (int j = 0; j < 8; ++j) {
      const int srow = oc*8 + j;
      const int chunk = (od >> 3) ^ ((srow >> 3) & 7);
      tmp[j] = sT[srow*64 + chunk*8 + (od & 7)];
    }
    *(short8*)&VT[(size_t)(b*1024 + dt*64 + od) * 2048 + st*64 + oc*8] = *(short8*)tmp;
  }
}

// ---------- causal flash attention v3: QBLK=64, 4 waves x 16 rows ----------
// Every wave active on every KV tile; softmax in exp2 domain; 3 blocks/CU by LDS.
__global__ __launch_bounds__(256) void attn_k(const unsigned short* __restrict__ QKV,
                                              const unsigned short* __restrict__ VT,
                                              unsigned short* __restrict__ Ob)
{
  const int LDQ = 3072;
  const float C2 = 0.125f * 1.44269504088896f;   // scale * log2(e)
  const int b = blockIdx.y >> 4, h = blockIdx.y & 15;
  const int qb = (31 - (int)blockIdx.x) * 64;
  const int tid = threadIdx.x;
  const int w = tid >> 6, l = tid & 63;
  const int l15 = l & 15, l4 = l >> 4;
  const int qw = qb + w * 16;                    // wave's 16 q-rows
  const unsigned short* Qg  = QKV + (size_t)(b * 2048) * LDQ + h * 64;
  const unsigned short* Kg  = Qg + 1024;
  const unsigned short* VTg = VT + (size_t)(b * 1024 + h * 64) * 2048;

  __shared__ unsigned short sK[2][4096];   // [64 k][64 d] chunk-swizzled
  __shared__ unsigned short sVT[2][4096];  // [64 d][64 k] chunk-swizzled
  __shared__ unsigned short sP[4][1152];   // per-wave [16][72]

  short8 qf[2];
  #pragma unroll
  for (int hc = 0; hc < 2; ++hc)
    qf[hc] = *(const short8*)&Qg[(size_t)(qw + l15) * LDQ + hc*32 + l4*8];

  const int rc0 = tid >> 3;
  const int ch0 = (tid & 7) ^ (rc0 & 7);
  const int rc1 = rc0 + 32;
  const unsigned short* Ks0 = Kg  + (size_t)rc0 * LDQ  + ch0 * 8;
  const unsigned short* Ks1 = Kg  + (size_t)rc1 * LDQ  + ch0 * 8;
  const unsigned short* Vs0 = VTg + (size_t)rc0 * 2048 + ch0 * 8;
  const unsigned short* Vs1 = VTg + (size_t)rc1 * 2048 + ch0 * 8;
  const int wun0 = w * 512;
  const int wun1 = 2048 + w * 512;

  f32x4 accO[4];
  float m_run[4], l_run[4];
  const f32x4 z4 = {0.f,0.f,0.f,0.f};
  #pragma unroll
  for (int dt = 0; dt < 4; ++dt) accO[dt] = z4;
  #pragma unroll
  for (int r = 0; r < 4; ++r) { m_run[r] = -1e30f; l_run[r] = 0.f; }

  const int ntB = (qb >> 6) + 1;
#define ASTAGE(buf, t) do { \
    const size_t ko = (size_t)(t) * 64 * LDQ; const int vo = (t) * 64; \
    gload_lds16(Ks0 + ko, &sK[buf][wun0]); \
    gload_lds16(Ks1 + ko, &sK[buf][wun1]); \
    gload_lds16(Vs0 + vo, &sVT[buf][wun0]); \
    gload_lds16(Vs1 + vo, &sVT[buf][wun1]); } while (0)

  ASTAGE(0, 0);
  __syncthreads();
  int cur = 0;
  for (int t = 0; t < ntB; ++t) {
    if (t + 1 < ntB) ASTAGE(cur ^ 1, t + 1);     // prefetch overlaps compute
    const int kv = t * 64;
    const unsigned short* Kb = sK[cur];
    const unsigned short* Vb = sVT[cur];
    const int lim = qw + 15 - kv;                // nt tile valid iff nt*16 <= lim
    f32x4 sAcc[4];
    #pragma unroll
    for (int nt = 0; nt < 4; ++nt) sAcc[nt] = z4;
    // ---- S = Q K^T ----
    __builtin_amdgcn_s_setprio(1);
    #pragma unroll
    for (int nt = 0; nt < 4; ++nt) {
      if (nt * 16 <= lim) {
        const int krow = nt*16 + l15;
        const short8 kf0 = *(const short8*)&Kb[krow*64 + ((l4 ^ (krow & 7)) * 8)];
        const short8 kf1 = *(const short8*)&Kb[krow*64 + (((4 + l4) ^ (krow & 7)) * 8)];
        sAcc[nt] = __builtin_amdgcn_mfma_f32_16x16x32_bf16(qf[0], kf0, sAcc[nt], 0,0,0);
        sAcc[nt] = __builtin_amdgcn_mfma_f32_16x16x32_bf16(qf[1], kf1, sAcc[nt], 0,0,0);
      }
    }
    __builtin_amdgcn_s_setprio(0);
    // ---- online softmax (exp2 domain, defer-max THR=8) ----
    const bool bound = (kv + 63 > qw);           // mask iff max col > MIN row (fix)
    float fac[4]; bool resc_any = false;
    #pragma unroll
    for (int r = 0; r < 4; ++r) {
      float sv[4];
      #pragma unroll
      for (int nt = 0; nt < 4; ++nt)
        sv[nt] = (nt * 16 <= lim) ? sAcc[nt][r] * C2 : -1e30f;
      if (bound) {
        const int row = l4*4 + r;
        #pragma unroll
        for (int nt = 0; nt < 4; ++nt)
          if (kv + nt*16 + l15 > qw + row) sv[nt] = -1e30f;
      }
      float mx = fmaxf(fmaxf(sv[0], sv[1]), fmaxf(sv[2], sv[3]));
      mx = fmaxf(mx, __shfl_xor(mx, 1));
      mx = fmaxf(mx, __shfl_xor(mx, 2));
      mx = fmaxf(mx, __shfl_xor(mx, 4));
      mx = fmaxf(mx, __shfl_xor(mx, 8));
      const float mo = m_run[r];
      const bool resc = mx > mo + 8.0f;
      const float mn = resc ? mx : mo;
      const float f = resc ? exp2f(mo - mn) : 1.0f;
      fac[r] = f; resc_any |= resc;
      const float p0 = exp2f(sv[0]-mn), p1 = exp2f(sv[1]-mn);
      const float p2 = exp2f(sv[2]-mn), p3 = exp2f(sv[3]-mn);
      float rs = (p0+p1)+(p2+p3);
      rs += __shfl_xor(rs,1); rs += __shfl_xor(rs,2);
      rs += __shfl_xor(rs,4); rs += __shfl_xor(rs,8);
      l_run[r] = l_run[r]*f + rs;
      m_run[r] = mn;
      const int prow = l4*4 + r;
      sP[w][prow*72      + l15] = f2b(p0);
      sP[w][prow*72 + 16 + l15] = f2b(p1);
      sP[w][prow*72 + 32 + l15] = f2b(p2);
      sP[w][prow*72 + 48 + l15] = f2b(p3);
    }
    if (__any(resc_any)) {
      #pragma unroll
      for (int dt = 0; dt < 4; ++dt)
        #pragma unroll
        for (int r = 0; r < 4; ++r)
          accO[dt][r] *= fac[r];
    }
    // ---- O += P V ----
    short8 pf[2];
    #pragma unroll
    for (int kc = 0; kc < 2; ++kc)
      pf[kc] = *(const short8*)&sP[w][l15*72 + kc*32 + l4*8];
    __builtin_amdgcn_s_setprio(1);
    #pragma unroll
    for (int dt = 0; dt < 4; ++dt) {
      const int vrow = dt*16 + l15;
      const short8 vf0 = *(const short8*)&Vb[vrow*64 + ((l4 ^ (vrow & 7)) * 8)];
      const short8 vf1 = *(const short8*)&Vb[vrow*64 + (((4 + l4) ^ (vrow & 7)) * 8)];
      accO[dt] = __builtin_amdgcn_mfma_f32_16x16x32_bf16(pf[0], vf0, accO[dt], 0,0,0);
      accO[dt] = __builtin_amdgcn_mfma_f32_16x16x32_bf16(pf[1], vf1, accO[dt], 0,0,0);
    }
    __builtin_amdgcn_s_setprio(0);
    __syncthreads();
    cur ^= 1;
  }
  #pragma unroll
  for (int dt = 0; dt < 4; ++dt)
    #pragma unroll
    for (int r = 0; r < 4; ++r) {
      const int row = qw + l4*4 + r;
      const float ov = accO[dt][r] / l_run[r];
      Ob[(size_t)(b*2048 + row) * 1024 + h*64 + dt*16 + l15] = f2b(ov);
    }
}

// ---------- launch ----------
extern "C" void kernel_launch(void* const* d_in, const int* in_sizes, int n_in,
                              void* d_out, int out_size, void* d_ws, size_t ws_size,
                              hipStream_t stream) {
  const float* x  = (const float*)d_in[0];
  const float* g1 = (const float*)d_in[1];
  const float* wq = (const float*)d_in[2];
  const float* wk = (const float*)d_in[3];
  const float* wv = (const float*)d_in[4];
  const float* wo = (const float*)d_in[5];
  const float* g2 = (const float*)d_in[6];
  const float* w1 = (const float*)d_in[7];
  const float* w2 = (const float*)d_in[8];   // dict order — w2 before w3
  const float* w3 = (const float*)d_in[9];
  float* out = (float*)d_out;
  char* ws = (char*)d_ws;
  (void)in_sizes; (void)n_in; (void)out_size; (void)ws_size;

  unsigned short* Wqkv = (unsigned short*)(ws + 0);          //  3072x1024 bf16
  unsigned short* Wo   = (unsigned short*)(ws + 6291456);    //  1024x1024
  unsigned short* W13  = (unsigned short*)(ws + 8388608);    //  8192x1024
  unsigned short* W2   = (unsigned short*)(ws + 25165824);   //  1024x4096
  unsigned short* XN   = (unsigned short*)(ws + 33554432);   //  4096x1024
  unsigned short* QKV  = (unsigned short*)(ws + 41943040);   //  4096x3072
  unsigned short* OB   = (unsigned short*)(ws + 67108864);   //  4096x1024
  unsigned short* VTb  = (unsigned short*)(ws + 75497472);   //  2x1024x2048 (dead window of P13)
  unsigned short* P13  = (unsigned short*)(ws + 41943040);   //  4096x8192 (reuse; written after attn)
  float*          H    = (float*)(ws + 109051904);           //  4096x1024 fp32

  cvt_k<<<1024, 256, 0, stream>>>(wq, Wqkv,             262144);
  cvt_k<<<1024, 256, 0, stream>>>(wk, Wqkv + 1048576,   262144);
  cvt_k<<<1024, 256, 0, stream>>>(wv, Wqkv + 2097152,   262144);
  cvt_k<<<1024, 256, 0, stream>>>(wo, Wo,               262144);
  cvt_k<<<4096, 256, 0, stream>>>(w1, W13,             1048576);
  cvt_k<<<4096, 256, 0, stream>>>(w3, W13 + 4194304,   1048576);
  cvt_k<<<4096, 256, 0, stream>>>(w2, W2,              1048576);

  rmsnorm_k<<<4096, 256, 0, stream>>>(x, g1, XN);
  gemm256_bt<<<dim3(12, 16), 512, 0, stream>>>(XN, Wqkv, 1024, 1024, QKV, 3072, 12);
  vtrans_k<<<dim3(32, 16, 2), 256, 0, stream>>>(QKV, VTb);
  attn_k<<<dim3(32, 32), 256, 0, stream>>>(QKV, VTb, OB);
  gemm_bt<1><<<dim3(8, 32), 256, 0, stream>>>(OB, Wo, 1024, 1024, 1024,
                                              nullptr, x, H, 1024);
  rmsnorm_k<<<4096, 256, 0, stream>>>(H, g2, XN);
  gemm256_bt<<<dim3(32, 16), 512, 0, stream>>>(XN, W13, 1024, 1024, P13, 8192, 32);
  gate_k<<<8192, 256, 0, stream>>>(P13);
  gemm_bt<1><<<dim3(8, 32), 256, 0, stream>>>(P13, W2, 1024, 4096, 8192,
                                              nullptr, H, out, 1024);
}

// Round 7
// 496.833 us; speedup vs baseline: 1.2135x; 1.2135x over previous
//
#include <hip/hip_runtime.h>

// ---------- types / helpers ----------
typedef __attribute__((ext_vector_type(8))) short short8;   // 8 x bf16 (4 VGPR)
typedef __attribute__((ext_vector_type(4))) float f32x4;    // MFMA acc

__device__ __forceinline__ unsigned short f2b(float f) {
  union { float f; unsigned u; } v; v.f = f;
  unsigned r = v.u + 0x7fffu + ((v.u >> 16) & 1u);   // RNE bf16
  return (unsigned short)(r >> 16);
}
__device__ __forceinline__ float b2f(unsigned short b) {
  union { unsigned u; float f; } v; v.u = ((unsigned)b) << 16; return v.f;
}

// async global->LDS, 16B per lane; lds dest = wave-uniform base + lane*16
__device__ __forceinline__ void gload_lds16(const void* g, void* l) {
  __builtin_amdgcn_global_load_lds(
      (const __attribute__((address_space(1))) void*)g,
      (__attribute__((address_space(3))) void*)l, 16, 0, 0);
}

// ---------- fp32 -> bf16 weight convert ----------
__global__ __launch_bounds__(256) void cvt_k(const float* __restrict__ s,
                                             unsigned short* __restrict__ d, int n4) {
  int i = blockIdx.x * 256 + threadIdx.x;
  if (i >= n4) return;
  float4 v = ((const float4*)s)[i];
  ushort4 o;
  o.x = f2b(v.x); o.y = f2b(v.y); o.z = f2b(v.z); o.w = f2b(v.w);
  ((ushort4*)d)[i] = o;
}

// ---------- RMSNorm (fp32 in -> bf16 out), one row per block ----------
__global__ __launch_bounds__(256) void rmsnorm_k(const float* __restrict__ x,
                                                 const float* __restrict__ g,
                                                 unsigned short* __restrict__ out) {
  const int row = blockIdx.x, tid = threadIdx.x;
  const float4 v = ((const float4*)(x + (size_t)row * 1024))[tid];
  float ss = v.x*v.x + v.y*v.y + v.z*v.z + v.w*v.w;
  #pragma unroll
  for (int d = 32; d > 0; d >>= 1) ss += __shfl_down(ss, d);
  __shared__ float red[4];
  if ((tid & 63) == 0) red[tid >> 6] = ss;
  __syncthreads();
  const float tot = red[0] + red[1] + red[2] + red[3];
  const float sc = rsqrtf(tot * (1.0f/1024.0f) + 1e-5f);
  const float4 gg = ((const float4*)g)[tid];
  ushort4 o;
  o.x = f2b(v.x * sc * gg.x); o.y = f2b(v.y * sc * gg.y);
  o.z = f2b(v.z * sc * gg.z); o.w = f2b(v.w * sc * gg.w);
  ((ushort4*)(out + (size_t)row * 1024))[tid] = o;
}

// ---------- SwiGLU gate: p1 <- silu(p1)*p3 ----------
__global__ __launch_bounds__(256) void gate_k(unsigned short* __restrict__ p13) {
  const size_t i = (size_t)blockIdx.x * 256 + threadIdx.x;
  const int r = (int)(i >> 9);
  const int fc = ((int)i & 511) * 8;
  unsigned short* p1 = p13 + (size_t)r * 8192 + fc;
  const unsigned short* p3 = p13 + (size_t)r * 8192 + 4096 + fc;
  ushort4 a0 = ((const ushort4*)p1)[0], a1 = ((const ushort4*)p1)[1];
  ushort4 b0 = ((const ushort4*)p3)[0], b1 = ((const ushort4*)p3)[1];
  unsigned short va[8] = {a0.x,a0.y,a0.z,a0.w,a1.x,a1.y,a1.z,a1.w};
  unsigned short vb[8] = {b0.x,b0.y,b0.z,b0.w,b1.x,b1.y,b1.z,b1.w};
  unsigned short vo[8];
  #pragma unroll
  for (int j = 0; j < 8; ++j) {
    float f1 = b2f(va[j]), f3 = b2f(vb[j]);
    float s = f1 / (1.0f + __expf(-f1));
    vo[j] = f2b(s * f3);
  }
  ushort4 o0 = {vo[0],vo[1],vo[2],vo[3]}, o1 = {vo[4],vo[5],vo[6],vo[7]};
  ((ushort4*)p1)[0] = o0; ((ushort4*)p1)[1] = o1;
}

// ---------- 128-tile GEMM (proven m97 structure): C = A * W^T ----------
template<int EPI>
__global__ __launch_bounds__(256) void gemm_bt(
    const unsigned short* __restrict__ A, const unsigned short* __restrict__ W,
    int N, int K, int lda,
    unsigned short* __restrict__ Cb, const float* __restrict__ res,
    float* __restrict__ Cf, int ldc)
{
  __shared__ unsigned short sA[4096];   // [128][32]
  __shared__ unsigned short sB[4096];   // [128][32]
  const int tid = threadIdx.x;
  const int w = tid >> 6, l = tid & 63;
  const int l15 = l & 15, l4 = l >> 4;
  const int bm = blockIdx.y * 128, bn = blockIdx.x * 128;
  const int wm = (w >> 1) * 64, wn = (w & 1) * 64;
  const int c0 = w * 128 + l;
  const int ra0 = c0 >> 2,        ka0 = (c0 & 3) * 8;
  const int ra1 = (c0 + 64) >> 2, ka1 = ((c0 + 64) & 3) * 8;
  const unsigned short* Ar0 = A + (size_t)(bm + ra0) * lda + ka0;
  const unsigned short* Ar1 = A + (size_t)(bm + ra1) * lda + ka1;
  const unsigned short* Wr0 = W + (size_t)(bn + ra0) * K + ka0;
  const unsigned short* Wr1 = W + (size_t)(bn + ra1) * K + ka1;
  f32x4 acc[4][4];
  const f32x4 z4 = {0.f, 0.f, 0.f, 0.f};
  #pragma unroll
  for (int i = 0; i < 4; ++i)
    #pragma unroll
    for (int j = 0; j < 4; ++j) acc[i][j] = z4;

  for (int kt = 0; kt < K; kt += 32) {
    gload_lds16(Ar0 + kt, &sA[w * 1024]);
    gload_lds16(Ar1 + kt, &sA[w * 1024 + 512]);
    gload_lds16(Wr0 + kt, &sB[w * 1024]);
    gload_lds16(Wr1 + kt, &sB[w * 1024 + 512]);
    __syncthreads();
    short8 af[4], bf[4];
    #pragma unroll
    for (int mi = 0; mi < 4; ++mi)
      af[mi] = *(const short8*)&sA[(wm + mi*16 + l15)*32 + l4*8];
    #pragma unroll
    for (int ni = 0; ni < 4; ++ni)
      bf[ni] = *(const short8*)&sB[(wn + ni*16 + l15)*32 + l4*8];
    #pragma unroll
    for (int mi = 0; mi < 4; ++mi)
      #pragma unroll
      for (int ni = 0; ni < 4; ++ni)
        acc[mi][ni] = __builtin_amdgcn_mfma_f32_16x16x32_bf16(af[mi], bf[ni], acc[mi][ni], 0, 0, 0);
    __syncthreads();
  }
  #pragma unroll
  for (int mi = 0; mi < 4; ++mi)
    #pragma unroll
    for (int ni = 0; ni < 4; ++ni) {
      const int row0 = bm + wm + mi*16 + l4*4;
      const int col  = bn + wn + ni*16 + l15;
      #pragma unroll
      for (int r = 0; r < 4; ++r) {
        const float v = acc[mi][ni][r];
        if (EPI == 0) {
          Cb[(size_t)(row0 + r) * ldc + col] = f2b(v);
        } else {
          const size_t o = (size_t)(row0 + r) * ldc + col;
          Cf[o] = res[o] + v;
        }
      }
    }
}

// ---------- 256-tile pipelined GEMM: C[M,N] = A[M,K] * W[N,K]^T, bf16 out ----------
__global__ __launch_bounds__(512, 2) void gemm256_bt(
    const unsigned short* __restrict__ A, const unsigned short* __restrict__ W,
    int K, int lda, unsigned short* __restrict__ Cb, int ldc, int nbx)
{
  __shared__ unsigned short sA[4][8192];   // per buf: 16 subtiles of 16x32
  __shared__ unsigned short sB[4][8192];
  const int tid = threadIdx.x;
  const int w = tid >> 6, l = tid & 63;
  const int l15 = l & 15, l4 = l >> 4;
  const int nwg = nbx * gridDim.y;
  const int flat = blockIdx.y * nbx + blockIdx.x;
  const int q8 = nwg >> 3;
  const int sw = (flat & 7) * q8 + (flat >> 3);
  const int bm = (sw / nbx) * 256, bn = (sw % nbx) * 256;

  int rowl[2], coll[2];
  #pragma unroll
  for (int i = 0; i < 2; ++i) {
    const int g = w * 128 + i * 64 + l;
    const int s = g >> 6, j = g & 63;
    const int r = j >> 2, c8 = (j & 3) * 8;
    rowl[i] = s * 16 + r;
    coll[i] = c8 ^ ((r & 8) << 1);
  }
  const unsigned short* As0 = A + (size_t)(bm + rowl[0]) * lda + coll[0];
  const unsigned short* As1 = A + (size_t)(bm + rowl[1]) * lda + coll[1];
  const unsigned short* Ws0 = W + (size_t)(bn + rowl[0]) * K + coll[0];
  const unsigned short* Ws1 = W + (size_t)(bn + rowl[1]) * K + coll[1];
  const int d0 = w * 1024, d1 = w * 1024 + 512;

  const int swzr = (l4 * 8) ^ ((l15 & 8) << 1);
  const int aoff = (w >> 2) * 4096 + l15 * 32 + swzr;
  const int boff = (w & 3) * 2048 + l15 * 32 + swzr;

  f32x4 acc[8][4];
  const f32x4 z4 = {0.f, 0.f, 0.f, 0.f};
  #pragma unroll
  for (int i = 0; i < 8; ++i)
    #pragma unroll
    for (int j = 0; j < 4; ++j) acc[i][j] = z4;

  const int NT = K >> 5;
  #pragma unroll
  for (int p = 0; p < 3; ++p) {
    const int ko = p * 32;
    gload_lds16(As0 + ko, &sA[p][d0]);
    gload_lds16(As1 + ko, &sA[p][d1]);
    gload_lds16(Ws0 + ko, &sB[p][d0]);
    gload_lds16(Ws1 + ko, &sB[p][d1]);
  }
  asm volatile("s_waitcnt vmcnt(8)" ::: "memory");
  __builtin_amdgcn_s_barrier();

  for (int t = 0; t < NT; ++t) {
    const unsigned short* a_ = sA[t & 3];
    const unsigned short* b_ = sB[t & 3];
    const bool st = (t + 3 < NT);
    const int nb = (t + 3) & 3;
    const int ko = (t + 3) * 32;
    short8 bfr[4], afr[4];
    #pragma unroll
    for (int ni = 0; ni < 4; ++ni) bfr[ni] = *(const short8*)&b_[boff + ni * 512];
    #pragma unroll
    for (int mi = 0; mi < 4; ++mi) afr[mi] = *(const short8*)&a_[aoff + mi * 512];
    if (st) { gload_lds16(As0 + ko, &sA[nb][d0]); gload_lds16(Ws0 + ko, &sB[nb][d0]); }
    __builtin_amdgcn_s_barrier();
    asm volatile("s_waitcnt lgkmcnt(0)" ::: "memory");
    __builtin_amdgcn_sched_barrier(0);
    __builtin_amdgcn_s_setprio(1);
    #pragma unroll
    for (int mi = 0; mi < 4; ++mi)
      #pragma unroll
      for (int ni = 0; ni < 4; ++ni)
        acc[mi][ni] = __builtin_amdgcn_mfma_f32_16x16x32_bf16(bfr[ni], afr[mi], acc[mi][ni], 0, 0, 0);
    __builtin_amdgcn_s_setprio(0);
    __builtin_amdgcn_s_barrier();
    #pragma unroll
    for (int mi = 0; mi < 4; ++mi) afr[mi] = *(const short8*)&a_[aoff + (mi + 4) * 512];
    if (st) { gload_lds16(As1 + ko, &sA[nb][d1]); gload_lds16(Ws1 + ko, &sB[nb][d1]); }
    __builtin_amdgcn_s_barrier();
    asm volatile("s_waitcnt lgkmcnt(0)" ::: "memory");
    __builtin_amdgcn_sched_barrier(0);
    __builtin_amdgcn_s_setprio(1);
    #pragma unroll
    for (int mi = 0; mi < 4; ++mi)
      #pragma unroll
      for (int ni = 0; ni < 4; ++ni)
        acc[mi + 4][ni] = __builtin_amdgcn_mfma_f32_16x16x32_bf16(bfr[ni], afr[mi], acc[mi + 4][ni], 0, 0, 0);
    __builtin_amdgcn_s_setprio(0);
    if (t < NT - 3)       asm volatile("s_waitcnt vmcnt(8)" ::: "memory");
    else if (t == NT - 3) asm volatile("s_waitcnt vmcnt(4)" ::: "memory");
    else                  asm volatile("s_waitcnt vmcnt(0)" ::: "memory");
    __builtin_amdgcn_s_barrier();
  }
  #pragma unroll
  for (int mi = 0; mi < 8; ++mi) {
    const int row = bm + (w >> 2) * 128 + mi * 16 + l15;
    #pragma unroll
    for (int ni = 0; ni < 4; ++ni) {
      const int col = bn + (w & 3) * 64 + ni * 16 + l4 * 4;
      ushort4 o = { f2b(acc[mi][ni][0]), f2b(acc[mi][ni][1]),
                    f2b(acc[mi][ni][2]), f2b(acc[mi][ni][3]) };
      *(ushort4*)&Cb[(size_t)row * ldc + col] = o;
    }
  }
}

// ---------- V transpose: VT[b][d][s] <- QKV v-part [b][s][d] ----------
__global__ __launch_bounds__(256) void vtrans_k(const unsigned short* __restrict__ QKV,
                                                unsigned short* __restrict__ VT) {
  __shared__ unsigned short sT[4096];  // [64 s][64 d], chunk-swizzled
  const int st = blockIdx.x, dt = blockIdx.y, b = blockIdx.z;
  const int tid = threadIdx.x;
  #pragma unroll
  for (int half = 0; half < 2; ++half) {
    const int c = tid + half * 256;
    const int r = c >> 3;              // s-local row
    const int ch = c & 7;              // d-chunk
    const unsigned short* src =
        QKV + (size_t)(b*2048 + st*64 + r) * 3072 + 2048 + dt*64 + ch*8;
    short8 v = *(const short8*)src;
    *(short8*)&sT[r*64 + ((ch ^ ((r >> 3) & 7)) * 8)] = v;
  }
  __syncthreads();
  #pragma unroll
  for (int half = 0; half < 2; ++half) {
    const int c = tid + half * 256;
    const int od = c >> 3;             // d-local row of VT
    const int oc = c & 7;              // s-chunk
    unsigned short tmp[8];
    #pragma unroll
    for (int j = 0; j < 8; ++j) {
      const int srow = oc*8 + j;
      const int chunk = (od >> 3) ^ ((srow >> 3) & 7);
      tmp[j] = sT[srow*64 + chunk*8 + (od & 7)];
    }
    *(short8*)&VT[(size_t)(b*1024 + dt*64 + od) * 2048 + st*64 + oc*8] = *(short8*)tmp;
  }
}

// ---------- causal flash attention v4 ----------
// Load-balanced: block bx handles q-tiles {bx, 31-bx} sequentially (33 KV-tile
// steps each, perfectly uniform). Swapped QK^T (mfma(K,Q) -> lane holds one
// q-row): softmax row-reduce = in-register tree + 2 shuffles. P packed as
// ds_write_b64. PV path unchanged; softmax state transposed via 4 shuffles
// only on rescale and at the epilogue.
__global__ __launch_bounds__(256) void attn_k(const unsigned short* __restrict__ QKV,
                                              const unsigned short* __restrict__ VT,
                                              unsigned short* __restrict__ Ob)
{
  const int LDQ = 3072;
  const float C2 = 0.125f * 1.44269504088896f;   // scale * log2(e)
  const int b = blockIdx.y >> 4, h = blockIdx.y & 15;
  const int tid = threadIdx.x;
  const int w = tid >> 6, l = tid & 63;
  const int l15 = l & 15, l4 = l >> 4;
  const unsigned short* Qg  = QKV + (size_t)(b * 2048) * LDQ + h * 64;
  const unsigned short* Kg  = Qg + 1024;
  const unsigned short* VTg = VT + (size_t)(b * 1024 + h * 64) * 2048;

  __shared__ unsigned short sK[2][4096];   // [64 k][64 d] chunk-swizzled
  __shared__ unsigned short sVT[2][4096];  // [64 d][64 k] chunk-swizzled
  __shared__ unsigned short sP[4][1152];   // per-wave [16][72]

  const int rc0 = tid >> 3;
  const int ch0 = (tid & 7) ^ (rc0 & 7);
  const int rc1 = rc0 + 32;
  const unsigned short* Ks0 = Kg  + (size_t)rc0 * LDQ  + ch0 * 8;
  const unsigned short* Ks1 = Kg  + (size_t)rc1 * LDQ  + ch0 * 8;
  const unsigned short* Vs0 = VTg + (size_t)rc0 * 2048 + ch0 * 8;
  const unsigned short* Vs1 = VTg + (size_t)rc1 * 2048 + ch0 * 8;
  const int wun0 = w * 512;
  const int wun1 = 2048 + w * 512;
  const f32x4 z4 = {0.f,0.f,0.f,0.f};

#define ASTAGE(buf, t) do { \
    const size_t ko = (size_t)(t) * 64 * LDQ; const int vo = (t) * 64; \
    gload_lds16(Ks0 + ko, &sK[buf][wun0]); \
    gload_lds16(Ks1 + ko, &sK[buf][wun1]); \
    gload_lds16(Vs0 + vo, &sVT[buf][wun0]); \
    gload_lds16(Vs1 + vo, &sVT[buf][wun1]); } while (0)

  #pragma unroll
  for (int qp = 0; qp < 2; ++qp) {
    const int qtile = (qp == 0) ? (31 - (int)blockIdx.x) : (int)blockIdx.x;
    const int qb = qtile * 64;
    const int qw = qb + w * 16;                  // wave's 16 q-rows
    short8 qf[2];
    #pragma unroll
    for (int hc = 0; hc < 2; ++hc)
      qf[hc] = *(const short8*)&Qg[(size_t)(qw + l15) * LDQ + hc*32 + l4*8];

    f32x4 accO[4];
    #pragma unroll
    for (int dt = 0; dt < 4; ++dt) accO[dt] = z4;
    float m_run = -1e30f, l_run = 0.f;           // per-lane row q = l15

    const int ntB = qtile + 1;
    ASTAGE(0, 0);
    __syncthreads();
    int cur = 0;
    for (int t = 0; t < ntB; ++t) {
      if (t + 1 < ntB) ASTAGE(cur ^ 1, t + 1);   // prefetch overlaps compute
      const int kv = t * 64;
      const unsigned short* Kb = sK[cur];
      const unsigned short* Vb = sVT[cur];
      const int lim = qw + 15 - kv;
      f32x4 sAcc[4];
      #pragma unroll
      for (int nt = 0; nt < 4; ++nt) sAcc[nt] = z4;
      // ---- S^T = K Q^T : lane holds S[k=kv+nt*16+l4*4+r][q=qw+l15] ----
      __builtin_amdgcn_s_setprio(1);
      #pragma unroll
      for (int nt = 0; nt < 4; ++nt) {
        if (nt * 16 <= lim) {
          const int krow = nt*16 + l15;
          const short8 kf0 = *(const short8*)&Kb[krow*64 + ((l4 ^ (krow & 7)) * 8)];
          const short8 kf1 = *(const short8*)&Kb[krow*64 + (((4 + l4) ^ (krow & 7)) * 8)];
          sAcc[nt] = __builtin_amdgcn_mfma_f32_16x16x32_bf16(kf0, qf[0], sAcc[nt], 0,0,0);
          sAcc[nt] = __builtin_amdgcn_mfma_f32_16x16x32_bf16(kf1, qf[1], sAcc[nt], 0,0,0);
        }
      }
      __builtin_amdgcn_s_setprio(0);
      // ---- online softmax, row-local (exp2 domain, defer-max THR=8) ----
      const bool bound = (kv + 63 > qw);
      float p[16];
      float mx = -1e30f;
      #pragma unroll
      for (int nt = 0; nt < 4; ++nt)
        #pragma unroll
        for (int r = 0; r < 4; ++r) {
          float s = (nt * 16 <= lim) ? sAcc[nt][r] * C2 : -1e30f;
          if (bound && (kv + nt*16 + l4*4 + r > qw + l15)) s = -1e30f;
          p[nt*4 + r] = s;
          mx = fmaxf(mx, s);
        }
      mx = fmaxf(mx, __shfl_xor(mx, 16));
      mx = fmaxf(mx, __shfl_xor(mx, 32));        // row max (dup across l4)
      const bool resc = mx > m_run + 8.0f;
      const float mn = resc ? mx : m_run;
      const float f = resc ? exp2f(m_run - mn) : 1.0f;
      m_run = mn;
      float rs = 0.f;
      #pragma unroll
      for (int j = 0; j < 16; ++j) { p[j] = exp2f(p[j] - mn); rs += p[j]; }
      rs += __shfl_xor(rs, 16);
      rs += __shfl_xor(rs, 32);                  // row sum
      l_run = l_run * f + rs;
      if (__any(resc)) {                         // transpose fac to accO rows
        float fr[4];
        #pragma unroll
        for (int r = 0; r < 4; ++r) fr[r] = __shfl(f, (l & 48) + l4*4 + r);
        #pragma unroll
        for (int dt = 0; dt < 4; ++dt)
          #pragma unroll
          for (int r = 0; r < 4; ++r) accO[dt][r] *= fr[r];
      }
      // ---- pack P -> sP[q=l15][k] (4x ds_write_b64) ----
      #pragma unroll
      for (int nt = 0; nt < 4; ++nt) {
        ushort4 pk = { f2b(p[nt*4]), f2b(p[nt*4+1]), f2b(p[nt*4+2]), f2b(p[nt*4+3]) };
        *(ushort4*)&sP[w][l15*72 + nt*16 + l4*4] = pk;
      }
      // ---- O += P V ----
      short8 pf[2];
      #pragma unroll
      for (int kc = 0; kc < 2; ++kc)
        pf[kc] = *(const short8*)&sP[w][l15*72 + kc*32 + l4*8];
      __builtin_amdgcn_s_setprio(1);
      #pragma unroll
      for (int dt = 0; dt < 4; ++dt) {
        const int vrow = dt*16 + l15;
        const short8 vf0 = *(const short8*)&Vb[vrow*64 + ((l4 ^ (vrow & 7)) * 8)];
        const short8 vf1 = *(const short8*)&Vb[vrow*64 + (((4 + l4) ^ (vrow & 7)) * 8)];
        accO[dt] = __builtin_amdgcn_mfma_f32_16x16x32_bf16(pf[0], vf0, accO[dt], 0,0,0);
        accO[dt] = __builtin_amdgcn_mfma_f32_16x16x32_bf16(pf[1], vf1, accO[dt], 0,0,0);
      }
      __builtin_amdgcn_s_setprio(0);
      __syncthreads();
      cur ^= 1;
    }
    // epilogue: accO rows are q = qw + l4*4 + r; softmax state rows are l15
    float lr[4];
    #pragma unroll
    for (int r = 0; r < 4; ++r) lr[r] = __shfl(l_run, (l & 48) + l4*4 + r);
    #pragma unroll
    for (int dt = 0; dt < 4; ++dt)
      #pragma unroll
      for (int r = 0; r < 4; ++r) {
        const int row = qw + l4*4 + r;
        Ob[(size_t)(b*2048 + row) * 1024 + h*64 + dt*16 + l15] = f2b(accO[dt][r] / lr[r]);
      }
  }
#undef ASTAGE
}

// ---------- launch ----------
extern "C" void kernel_launch(void* const* d_in, const int* in_sizes, int n_in,
                              void* d_out, int out_size, void* d_ws, size_t ws_size,
                              hipStream_t stream) {
  const float* x  = (const float*)d_in[0];
  const float* g1 = (const float*)d_in[1];
  const float* wq = (const float*)d_in[2];
  const float* wk = (const float*)d_in[3];
  const float* wv = (const float*)d_in[4];
  const float* wo = (const float*)d_in[5];
  const float* g2 = (const float*)d_in[6];
  const float* w1 = (const float*)d_in[7];
  const float* w2 = (const float*)d_in[8];   // dict order — w2 before w3
  const float* w3 = (const float*)d_in[9];
  float* out = (float*)d_out;
  char* ws = (char*)d_ws;
  (void)in_sizes; (void)n_in; (void)out_size; (void)ws_size;

  unsigned short* Wqkv = (unsigned short*)(ws + 0);          //  3072x1024 bf16
  unsigned short* Wo   = (unsigned short*)(ws + 6291456);    //  1024x1024
  unsigned short* W13  = (unsigned short*)(ws + 8388608);    //  8192x1024
  unsigned short* W2   = (unsigned short*)(ws + 25165824);   //  1024x4096
  unsigned short* XN   = (unsigned short*)(ws + 33554432);   //  4096x1024
  unsigned short* QKV  = (unsigned short*)(ws + 41943040);   //  4096x3072
  unsigned short* OB   = (unsigned short*)(ws + 67108864);   //  4096x1024
  unsigned short* VTb  = (unsigned short*)(ws + 75497472);   //  2x1024x2048 (dead window of P13)
  unsigned short* P13  = (unsigned short*)(ws + 41943040);   //  4096x8192 (reuse; written after attn)
  float*          H    = (float*)(ws + 109051904);           //  4096x1024 fp32

  cvt_k<<<1024, 256, 0, stream>>>(wq, Wqkv,             262144);
  cvt_k<<<1024, 256, 0, stream>>>(wk, Wqkv + 1048576,   262144);
  cvt_k<<<1024, 256, 0, stream>>>(wv, Wqkv + 2097152,   262144);
  cvt_k<<<1024, 256, 0, stream>>>(wo, Wo,               262144);
  cvt_k<<<4096, 256, 0, stream>>>(w1, W13,             1048576);
  cvt_k<<<4096, 256, 0, stream>>>(w3, W13 + 4194304,   1048576);
  cvt_k<<<4096, 256, 0, stream>>>(w2, W2,              1048576);

  rmsnorm_k<<<4096, 256, 0, stream>>>(x, g1, XN);
  gemm256_bt<<<dim3(12, 16), 512, 0, stream>>>(XN, Wqkv, 1024, 1024, QKV, 3072, 12);
  vtrans_k<<<dim3(32, 16, 2), 256, 0, stream>>>(QKV, VTb);
  attn_k<<<dim3(16, 32), 256, 0, stream>>>(QKV, VTb, OB);
  gemm_bt<1><<<dim3(8, 32), 256, 0, stream>>>(OB, Wo, 1024, 1024, 1024,
                                              nullptr, x, H, 1024);
  rmsnorm_k<<<4096, 256, 0, stream>>>(H, g2, XN);
  gemm256_bt<<<dim3(32, 16), 512, 0, stream>>>(XN, W13, 1024, 1024, P13, 8192, 32);
  gate_k<<<8192, 256, 0, stream>>>(P13);
  gemm_bt<1><<<dim3(8, 32), 256, 0, stream>>>(P13, W2, 1024, 4096, 8192,
                                              nullptr, H, out, 1024);
}

// Round 9
// 481.138 us; speedup vs baseline: 1.2531x; 1.0326x over previous
//
#include <hip/hip_runtime.h>

// ---------- types / helpers ----------
typedef __attribute__((ext_vector_type(8))) short short8;   // 8 x bf16 (4 VGPR)
typedef __attribute__((ext_vector_type(4))) float f32x4;    // MFMA acc

__device__ __forceinline__ unsigned short f2b(float f) {
  union { float f; unsigned u; } v; v.f = f;
  unsigned r = v.u + 0x7fffu + ((v.u >> 16) & 1u);   // RNE bf16
  return (unsigned short)(r >> 16);
}
__device__ __forceinline__ float b2f(unsigned short b) {
  union { unsigned u; float f; } v; v.u = ((unsigned)b) << 16; return v.f;
}

// async global->LDS, 16B per lane; lds dest = wave-uniform base + lane*16
__device__ __forceinline__ void gload_lds16(const void* g, void* l) {
  __builtin_amdgcn_global_load_lds(
      (const __attribute__((address_space(1))) void*)g,
      (__attribute__((address_space(3))) void*)l, 16, 0, 0);
}

// ---------- fp32 -> bf16 weight convert ----------
__global__ __launch_bounds__(256) void cvt_k(const float* __restrict__ s,
                                             unsigned short* __restrict__ d, int n4) {
  int i = blockIdx.x * 256 + threadIdx.x;
  if (i >= n4) return;
  float4 v = ((const float4*)s)[i];
  ushort4 o;
  o.x = f2b(v.x); o.y = f2b(v.y); o.z = f2b(v.z); o.w = f2b(v.w);
  ((ushort4*)d)[i] = o;
}

// ---------- RMSNorm (fp32 in -> bf16 out), one row per block ----------
__global__ __launch_bounds__(256) void rmsnorm_k(const float* __restrict__ x,
                                                 const float* __restrict__ g,
                                                 unsigned short* __restrict__ out) {
  const int row = blockIdx.x, tid = threadIdx.x;
  const float4 v = ((const float4*)(x + (size_t)row * 1024))[tid];
  float ss = v.x*v.x + v.y*v.y + v.z*v.z + v.w*v.w;
  #pragma unroll
  for (int d = 32; d > 0; d >>= 1) ss += __shfl_down(ss, d);
  __shared__ float red[4];
  if ((tid & 63) == 0) red[tid >> 6] = ss;
  __syncthreads();
  const float tot = red[0] + red[1] + red[2] + red[3];
  const float sc = rsqrtf(tot * (1.0f/1024.0f) + 1e-5f);
  const float4 gg = ((const float4*)g)[tid];
  ushort4 o;
  o.x = f2b(v.x * sc * gg.x); o.y = f2b(v.y * sc * gg.y);
  o.z = f2b(v.z * sc * gg.z); o.w = f2b(v.w * sc * gg.w);
  ((ushort4*)(out + (size_t)row * 1024))[tid] = o;
}

// ---------- SwiGLU gate: p1 <- silu(p1)*p3 ----------
__global__ __launch_bounds__(256) void gate_k(unsigned short* __restrict__ p13) {
  const size_t i = (size_t)blockIdx.x * 256 + threadIdx.x;
  const int r = (int)(i >> 9);
  const int fc = ((int)i & 511) * 8;
  unsigned short* p1 = p13 + (size_t)r * 8192 + fc;
  const unsigned short* p3 = p13 + (size_t)r * 8192 + 4096 + fc;
  ushort4 a0 = ((const ushort4*)p1)[0], a1 = ((const ushort4*)p1)[1];
  ushort4 b0 = ((const ushort4*)p3)[0], b1 = ((const ushort4*)p3)[1];
  unsigned short va[8] = {a0.x,a0.y,a0.z,a0.w,a1.x,a1.y,a1.z,a1.w};
  unsigned short vb[8] = {b0.x,b0.y,b0.z,b0.w,b1.x,b1.y,b1.z,b1.w};
  unsigned short vo[8];
  #pragma unroll
  for (int j = 0; j < 8; ++j) {
    float f1 = b2f(va[j]), f3 = b2f(vb[j]);
    float s = f1 / (1.0f + __expf(-f1));
    vo[j] = f2b(s * f3);
  }
  ushort4 o0 = {vo[0],vo[1],vo[2],vo[3]}, o1 = {vo[4],vo[5],vo[6],vo[7]};
  ((ushort4*)p1)[0] = o0; ((ushort4*)p1)[1] = o1;
}

// ---------- 128-tile pipelined GEMM: C[M,N] = A[M,K] * W[N,K]^T ----------
// gemm256 schedule at 128^2: 4 rotating LDS bufs (64 KiB), counted vmcnt
// (8 steady / 4 / 0 drain), 1 barrier per K-step, st_16x32 swizzle pair,
// swapped-operand MFMA -> C^T frags -> vectorized epilogue.
// EPI 0: bf16 store. EPI 1: Cf = res + C (fp32, float4).
template<int EPI>
__global__ __launch_bounds__(256, 2) void gemm128p(
    const unsigned short* __restrict__ A, const unsigned short* __restrict__ W,
    int K, int lda, unsigned short* __restrict__ Cb, const float* __restrict__ res,
    float* __restrict__ Cf, int ldc, int nbx)
{
  __shared__ unsigned short sA[4][4096];   // per buf: 8 subtiles of 16x32
  __shared__ unsigned short sB[4][4096];
  const int tid = threadIdx.x;
  const int w = tid >> 6, l = tid & 63;
  const int l15 = l & 15, l4 = l >> 4;
  // bijective XCD swizzle (nwg % 8 == 0 for all call sites)
  const int nwg = nbx * gridDim.y;
  const int flat = blockIdx.y * nbx + blockIdx.x;
  const int q8 = nwg >> 3;
  const int sw = (flat & 7) * q8 + (flat >> 3);
  const int bm = (sw / nbx) * 128, bn = (sw % nbx) * 128;
  const int wm = (w >> 1) * 64, wn = (w & 1) * 64;

  // staging: 512 chunks/array; thread covers chunks w*64+l and 256+w*64+l
  int rowl[2], coll[2];
  #pragma unroll
  for (int i = 0; i < 2; ++i) {
    const int g = i * 256 + w * 64 + l;
    const int s = g >> 6, j = g & 63;
    const int r = j >> 2, c8 = (j & 3) * 8;
    rowl[i] = s * 16 + r;
    coll[i] = c8 ^ ((r & 8) << 1);     // inverse swizzle on source (involution)
  }
  const unsigned short* As0 = A + (size_t)(bm + rowl[0]) * lda + coll[0];
  const unsigned short* As1 = A + (size_t)(bm + rowl[1]) * lda + coll[1];
  const unsigned short* Ws0 = W + (size_t)(bn + rowl[0]) * K + coll[0];
  const unsigned short* Ws1 = W + (size_t)(bn + rowl[1]) * K + coll[1];
  const int d0 = w * 512, d1 = 2048 + w * 512;   // wave-uniform LDS dests (elems)

  // swizzled ds_read: subtile*512 + l15*32 + (l4*8 ^ ((l15&8)<<1))
  const int swzr = (l4 * 8) ^ ((l15 & 8) << 1);
  const int aoff = (w >> 1) * 2048 + l15 * 32 + swzr;   // + mi*512
  const int boff = (w & 1) * 2048 + l15 * 32 + swzr;    // + ni*512

  f32x4 acc[4][4];
  const f32x4 z4 = {0.f, 0.f, 0.f, 0.f};
  #pragma unroll
  for (int i = 0; i < 4; ++i)
    #pragma unroll
    for (int j = 0; j < 4; ++j) acc[i][j] = z4;

  const int NT = K >> 5;
  #pragma unroll
  for (int p = 0; p < 3; ++p) {      // prologue: tiles 0,1,2 -> bufs 0,1,2
    const size_t ko = (size_t)p * 32;
    gload_lds16(As0 + ko, &sA[p][d0]);
    gload_lds16(As1 + ko, &sA[p][d1]);
    gload_lds16(Ws0 + ko, &sB[p][d0]);
    gload_lds16(Ws1 + ko, &sB[p][d1]);
  }
  asm volatile("s_waitcnt vmcnt(8)" ::: "memory");   // tile 0 landed
  __builtin_amdgcn_s_barrier();

  for (int t = 0; t < NT; ++t) {
    const unsigned short* a_ = sA[t & 3];
    const unsigned short* b_ = sB[t & 3];
    if (t + 3 < NT) {
      const int nb = (t + 3) & 3;
      const size_t ko = (size_t)(t + 3) * 32;
      gload_lds16(As0 + ko, &sA[nb][d0]);
      gload_lds16(As1 + ko, &sA[nb][d1]);
      gload_lds16(Ws0 + ko, &sB[nb][d0]);
      gload_lds16(Ws1 + ko, &sB[nb][d1]);
    }
    short8 afr[4], bfr[4];
    #pragma unroll
    for (int ni = 0; ni < 4; ++ni) bfr[ni] = *(const short8*)&b_[boff + ni * 512];
    #pragma unroll
    for (int mi = 0; mi < 4; ++mi) afr[mi] = *(const short8*)&a_[aoff + mi * 512];
    asm volatile("s_waitcnt lgkmcnt(0)" ::: "memory");
    __builtin_amdgcn_sched_barrier(0);
    __builtin_amdgcn_s_setprio(1);
    #pragma unroll
    for (int mi = 0; mi < 4; ++mi)
      #pragma unroll
      for (int ni = 0; ni < 4; ++ni)   // swapped operands -> C^T fragments
        acc[mi][ni] = __builtin_amdgcn_mfma_f32_16x16x32_bf16(bfr[ni], afr[mi], acc[mi][ni], 0, 0, 0);
    __builtin_amdgcn_s_setprio(0);
    if (t < NT - 3)       asm volatile("s_waitcnt vmcnt(8)" ::: "memory");
    else if (t == NT - 3) asm volatile("s_waitcnt vmcnt(4)" ::: "memory");
    else                  asm volatile("s_waitcnt vmcnt(0)" ::: "memory");
    __builtin_amdgcn_s_barrier();
  }
  // epilogue: acc[mi][ni][r] = C[bm+wm+mi*16+l15][bn+wn+ni*16+l4*4+r]
  #pragma unroll
  for (int mi = 0; mi < 4; ++mi) {
    const int row = bm + wm + mi * 16 + l15;
    #pragma unroll
    for (int ni = 0; ni < 4; ++ni) {
      const int col = bn + wn + ni * 16 + l4 * 4;
      if (EPI == 0) {
        ushort4 o = { f2b(acc[mi][ni][0]), f2b(acc[mi][ni][1]),
                      f2b(acc[mi][ni][2]), f2b(acc[mi][ni][3]) };
        *(ushort4*)&Cb[(size_t)row * ldc + col] = o;
      } else {
        const size_t o = (size_t)row * ldc + col;
        const float4 rv = *(const float4*)&res[o];
        float4 ov = { rv.x + acc[mi][ni][0], rv.y + acc[mi][ni][1],
                      rv.z + acc[mi][ni][2], rv.w + acc[mi][ni][3] };
        *(float4*)&Cf[o] = ov;
      }
    }
  }
}

// ---------- 256-tile pipelined GEMM: C[M,N] = A[M,K] * W[N,K]^T, bf16 out ----------
__global__ __launch_bounds__(512, 2) void gemm256_bt(
    const unsigned short* __restrict__ A, const unsigned short* __restrict__ W,
    int K, int lda, unsigned short* __restrict__ Cb, int ldc, int nbx)
{
  __shared__ unsigned short sA[4][8192];   // per buf: 16 subtiles of 16x32
  __shared__ unsigned short sB[4][8192];
  const int tid = threadIdx.x;
  const int w = tid >> 6, l = tid & 63;
  const int l15 = l & 15, l4 = l >> 4;
  const int nwg = nbx * gridDim.y;
  const int flat = blockIdx.y * nbx + blockIdx.x;
  const int q8 = nwg >> 3;
  const int sw = (flat & 7) * q8 + (flat >> 3);
  const int bm = (sw / nbx) * 256, bn = (sw % nbx) * 256;

  int rowl[2], coll[2];
  #pragma unroll
  for (int i = 0; i < 2; ++i) {
    const int g = w * 128 + i * 64 + l;
    const int s = g >> 6, j = g & 63;
    const int r = j >> 2, c8 = (j & 3) * 8;
    rowl[i] = s * 16 + r;
    coll[i] = c8 ^ ((r & 8) << 1);
  }
  const unsigned short* As0 = A + (size_t)(bm + rowl[0]) * lda + coll[0];
  const unsigned short* As1 = A + (size_t)(bm + rowl[1]) * lda + coll[1];
  const unsigned short* Ws0 = W + (size_t)(bn + rowl[0]) * K + coll[0];
  const unsigned short* Ws1 = W + (size_t)(bn + rowl[1]) * K + coll[1];
  const int d0 = w * 1024, d1 = w * 1024 + 512;

  const int swzr = (l4 * 8) ^ ((l15 & 8) << 1);
  const int aoff = (w >> 2) * 4096 + l15 * 32 + swzr;
  const int boff = (w & 3) * 2048 + l15 * 32 + swzr;

  f32x4 acc[8][4];
  const f32x4 z4 = {0.f, 0.f, 0.f, 0.f};
  #pragma unroll
  for (int i = 0; i < 8; ++i)
    #pragma unroll
    for (int j = 0; j < 4; ++j) acc[i][j] = z4;

  const int NT = K >> 5;
  #pragma unroll
  for (int p = 0; p < 3; ++p) {
    const int ko = p * 32;
    gload_lds16(As0 + ko, &sA[p][d0]);
    gload_lds16(As1 + ko, &sA[p][d1]);
    gload_lds16(Ws0 + ko, &sB[p][d0]);
    gload_lds16(Ws1 + ko, &sB[p][d1]);
  }
  asm volatile("s_waitcnt vmcnt(8)" ::: "memory");
  __builtin_amdgcn_s_barrier();

  for (int t = 0; t < NT; ++t) {
    const unsigned short* a_ = sA[t & 3];
    const unsigned short* b_ = sB[t & 3];
    const bool st = (t + 3 < NT);
    const int nb = (t + 3) & 3;
    const int ko = (t + 3) * 32;
    short8 bfr[4], afr[4];
    #pragma unroll
    for (int ni = 0; ni < 4; ++ni) bfr[ni] = *(const short8*)&b_[boff + ni * 512];
    #pragma unroll
    for (int mi = 0; mi < 4; ++mi) afr[mi] = *(const short8*)&a_[aoff + mi * 512];
    if (st) { gload_lds16(As0 + ko, &sA[nb][d0]); gload_lds16(Ws0 + ko, &sB[nb][d0]); }
    __builtin_amdgcn_s_barrier();
    asm volatile("s_waitcnt lgkmcnt(0)" ::: "memory");
    __builtin_amdgcn_sched_barrier(0);
    __builtin_amdgcn_s_setprio(1);
    #pragma unroll
    for (int mi = 0; mi < 4; ++mi)
      #pragma unroll
      for (int ni = 0; ni < 4; ++ni)
        acc[mi][ni] = __builtin_amdgcn_mfma_f32_16x16x32_bf16(bfr[ni], afr[mi], acc[mi][ni], 0, 0, 0);
    __builtin_amdgcn_s_setprio(0);
    __builtin_amdgcn_s_barrier();
    #pragma unroll
    for (int mi = 0; mi < 4; ++mi) afr[mi] = *(const short8*)&a_[aoff + (mi + 4) * 512];
    if (st) { gload_lds16(As1 + ko, &sA[nb][d1]); gload_lds16(Ws1 + ko, &sB[nb][d1]); }
    __builtin_amdgcn_s_barrier();
    asm volatile("s_waitcnt lgkmcnt(0)" ::: "memory");
    __builtin_amdgcn_sched_barrier(0);
    __builtin_amdgcn_s_setprio(1);
    #pragma unroll
    for (int mi = 0; mi < 4; ++mi)
      #pragma unroll
      for (int ni = 0; ni < 4; ++ni)
        acc[mi + 4][ni] = __builtin_amdgcn_mfma_f32_16x16x32_bf16(bfr[ni], afr[mi], acc[mi + 4][ni], 0, 0, 0);
    __builtin_amdgcn_s_setprio(0);
    if (t < NT - 3)       asm volatile("s_waitcnt vmcnt(8)" ::: "memory");
    else if (t == NT - 3) asm volatile("s_waitcnt vmcnt(4)" ::: "memory");
    else                  asm volatile("s_waitcnt vmcnt(0)" ::: "memory");
    __builtin_amdgcn_s_barrier();
  }
  #pragma unroll
  for (int mi = 0; mi < 8; ++mi) {
    const int row = bm + (w >> 2) * 128 + mi * 16 + l15;
    #pragma unroll
    for (int ni = 0; ni < 4; ++ni) {
      const int col = bn + (w & 3) * 64 + ni * 16 + l4 * 4;
      ushort4 o = { f2b(acc[mi][ni][0]), f2b(acc[mi][ni][1]),
                    f2b(acc[mi][ni][2]), f2b(acc[mi][ni][3]) };
      *(ushort4*)&Cb[(size_t)row * ldc + col] = o;
    }
  }
}

// ---------- V transpose: VT[b][d][s] <- QKV v-part [b][s][d] ----------
__global__ __launch_bounds__(256) void vtrans_k(const unsigned short* __restrict__ QKV,
                                                unsigned short* __restrict__ VT) {
  __shared__ unsigned short sT[4096];  // [64 s][64 d], chunk-swizzled
  const int st = blockIdx.x, dt = blockIdx.y, b = blockIdx.z;
  const int tid = threadIdx.x;
  #pragma unroll
  for (int half = 0; half < 2; ++half) {
    const int c = tid + half * 256;
    const int r = c >> 3;              // s-local row
    const int ch = c & 7;              // d-chunk
    const unsigned short* src =
        QKV + (size_t)(b*2048 + st*64 + r) * 3072 + 2048 + dt*64 + ch*8;
    short8 v = *(const short8*)src;
    *(short8*)&sT[r*64 + ((ch ^ ((r >> 3) & 7)) * 8)] = v;
  }
  __syncthreads();
  #pragma unroll
  for (int half = 0; half < 2; ++half) {
    const int c = tid + half * 256;
    const int od = c >> 3;             // d-local row of VT
    const int oc = c & 7;              // s-chunk
    unsigned short tmp[8];
    #pragma unroll
    for (int j = 0; j < 8; ++j) {
      const int srow = oc*8 + j;
      const int chunk = (od >> 3) ^ ((srow >> 3) & 7);
      tmp[j] = sT[srow*64 + chunk*8 + (od & 7)];
    }
    *(short8*)&VT[(size_t)(b*1024 + dt*64 + od) * 2048 + st*64 + oc*8] = *(short8*)tmp;
  }
}

// ---------- causal flash attention v4 (load-balanced, swapped QK^T) ----------
__global__ __launch_bounds__(256) void attn_k(const unsigned short* __restrict__ QKV,
                                              const unsigned short* __restrict__ VT,
                                              unsigned short* __restrict__ Ob)
{
  const int LDQ = 3072;
  const float C2 = 0.125f * 1.44269504088896f;   // scale * log2(e)
  const int b = blockIdx.y >> 4, h = blockIdx.y & 15;
  const int tid = threadIdx.x;
  const int w = tid >> 6, l = tid & 63;
  const int l15 = l & 15, l4 = l >> 4;
  const unsigned short* Qg  = QKV + (size_t)(b * 2048) * LDQ + h * 64;
  const unsigned short* Kg  = Qg + 1024;
  const unsigned short* VTg = VT + (size_t)(b * 1024 + h * 64) * 2048;

  __shared__ unsigned short sK[2][4096];   // [64 k][64 d] chunk-swizzled
  __shared__ unsigned short sVT[2][4096];  // [64 d][64 k] chunk-swizzled
  __shared__ unsigned short sP[4][1152];   // per-wave [16][72]

  const int rc0 = tid >> 3;
  const int ch0 = (tid & 7) ^ (rc0 & 7);
  const int rc1 = rc0 + 32;
  const unsigned short* Ks0 = Kg  + (size_t)rc0 * LDQ  + ch0 * 8;
  const unsigned short* Ks1 = Kg  + (size_t)rc1 * LDQ  + ch0 * 8;
  const unsigned short* Vs0 = VTg + (size_t)rc0 * 2048 + ch0 * 8;
  const unsigned short* Vs1 = VTg + (size_t)rc1 * 2048 + ch0 * 8;
  const int wun0 = w * 512;
  const int wun1 = 2048 + w * 512;
  const f32x4 z4 = {0.f,0.f,0.f,0.f};

#define ASTAGE(buf, t) do { \
    const size_t ko = (size_t)(t) * 64 * LDQ; const int vo = (t) * 64; \
    gload_lds16(Ks0 + ko, &sK[buf][wun0]); \
    gload_lds16(Ks1 + ko, &sK[buf][wun1]); \
    gload_lds16(Vs0 + vo, &sVT[buf][wun0]); \
    gload_lds16(Vs1 + vo, &sVT[buf][wun1]); } while (0)

  #pragma unroll
  for (int qp = 0; qp < 2; ++qp) {
    const int qtile = (qp == 0) ? (31 - (int)blockIdx.x) : (int)blockIdx.x;
    const int qb = qtile * 64;
    const int qw = qb + w * 16;                  // wave's 16 q-rows
    short8 qf[2];
    #pragma unroll
    for (int hc = 0; hc < 2; ++hc)
      qf[hc] = *(const short8*)&Qg[(size_t)(qw + l15) * LDQ + hc*32 + l4*8];

    f32x4 accO[4];
    #pragma unroll
    for (int dt = 0; dt < 4; ++dt) accO[dt] = z4;
    float m_run = -1e30f, l_run = 0.f;           // per-lane row q = l15

    const int ntB = qtile + 1;
    ASTAGE(0, 0);
    __syncthreads();
    int cur = 0;
    for (int t = 0; t < ntB; ++t) {
      if (t + 1 < ntB) ASTAGE(cur ^ 1, t + 1);   // prefetch overlaps compute
      const int kv = t * 64;
      const unsigned short* Kb = sK[cur];
      const unsigned short* Vb = sVT[cur];
      const int lim = qw + 15 - kv;
      f32x4 sAcc[4];
      #pragma unroll
      for (int nt = 0; nt < 4; ++nt) sAcc[nt] = z4;
      // ---- S^T = K Q^T : lane holds S[k=kv+nt*16+l4*4+r][q=qw+l15] ----
      __builtin_amdgcn_s_setprio(1);
      #pragma unroll
      for (int nt = 0; nt < 4; ++nt) {
        if (nt * 16 <= lim) {
          const int krow = nt*16 + l15;
          const short8 kf0 = *(const short8*)&Kb[krow*64 + ((l4 ^ (krow & 7)) * 8)];
          const short8 kf1 = *(const short8*)&Kb[krow*64 + (((4 + l4) ^ (krow & 7)) * 8)];
          sAcc[nt] = __builtin_amdgcn_mfma_f32_16x16x32_bf16(kf0, qf[0], sAcc[nt], 0,0,0);
          sAcc[nt] = __builtin_amdgcn_mfma_f32_16x16x32_bf16(kf1, qf[1], sAcc[nt], 0,0,0);
        }
      }
      __builtin_amdgcn_s_setprio(0);
      // ---- online softmax, row-local (exp2 domain, defer-max THR=8) ----
      const bool bound = (kv + 63 > qw);
      float p[16];
      float mx = -1e30f;
      #pragma unroll
      for (int nt = 0; nt < 4; ++nt)
        #pragma unroll
        for (int r = 0; r < 4; ++r) {
          float s = (nt * 16 <= lim) ? sAcc[nt][r] * C2 : -1e30f;
          if (bound && (kv + nt*16 + l4*4 + r > qw + l15)) s = -1e30f;
          p[nt*4 + r] = s;
          mx = fmaxf(mx, s);
        }
      mx = fmaxf(mx, __shfl_xor(mx, 16));
      mx = fmaxf(mx, __shfl_xor(mx, 32));        // row max (dup across l4)
      const bool resc = mx > m_run + 8.0f;
      const float mn = resc ? mx : m_run;
      const float f = resc ? exp2f(m_run - mn) : 1.0f;
      m_run = mn;
      float rs = 0.f;
      #pragma unroll
      for (int j = 0; j < 16; ++j) { p[j] = exp2f(p[j] - mn); rs += p[j]; }
      rs += __shfl_xor(rs, 16);
      rs += __shfl_xor(rs, 32);                  // row sum
      l_run = l_run * f + rs;
      if (__any(resc)) {                         // transpose fac to accO rows
        float fr[4];
        #pragma unroll
        for (int r = 0; r < 4; ++r) fr[r] = __shfl(f, (l & 48) + l4*4 + r);
        #pragma unroll
        for (int dt = 0; dt < 4; ++dt)
          #pragma unroll
          for (int r = 0; r < 4; ++r) accO[dt][r] *= fr[r];
      }
      // ---- pack P -> sP[q=l15][k] (4x ds_write_b64) ----
      #pragma unroll
      for (int nt = 0; nt < 4; ++nt) {
        ushort4 pk = { f2b(p[nt*4]), f2b(p[nt*4+1]), f2b(p[nt*4+2]), f2b(p[nt*4+3]) };
        *(ushort4*)&sP[w][l15*72 + nt*16 + l4*4] = pk;
      }
      // ---- O += P V ----
      short8 pf[2];
      #pragma unroll
      for (int kc = 0; kc < 2; ++kc)
        pf[kc] = *(const short8*)&sP[w][l15*72 + kc*32 + l4*8];
      __builtin_amdgcn_s_setprio(1);
      #pragma unroll
      for (int dt = 0; dt < 4; ++dt) {
        const int vrow = dt*16 + l15;
        const short8 vf0 = *(const short8*)&Vb[vrow*64 + ((l4 ^ (vrow & 7)) * 8)];
        const short8 vf1 = *(const short8*)&Vb[vrow*64 + (((4 + l4) ^ (vrow & 7)) * 8)];
        accO[dt] = __builtin_amdgcn_mfma_f32_16x16x32_bf16(pf[0], vf0, accO[dt], 0,0,0);
        accO[dt] = __builtin_amdgcn_mfma_f32_16x16x32_bf16(pf[1], vf1, accO[dt], 0,0,0);
      }
      __builtin_amdgcn_s_setprio(0);
      __syncthreads();
      cur ^= 1;
    }
    // epilogue: accO rows are q = qw + l4*4 + r; softmax state rows are l15
    float lr[4];
    #pragma unroll
    for (int r = 0; r < 4; ++r) lr[r] = __shfl(l_run, (l & 48) + l4*4 + r);
    #pragma unroll
    for (int dt = 0; dt < 4; ++dt)
      #pragma unroll
      for (int r = 0; r < 4; ++r) {
        const int row = qw + l4*4 + r;
        Ob[(size_t)(b*2048 + row) * 1024 + h*64 + dt*16 + l15] = f2b(accO[dt][r] / lr[r]);
      }
  }
#undef ASTAGE
}

// ---------- launch ----------
extern "C" void kernel_launch(void* const* d_in, const int* in_sizes, int n_in,
                              void* d_out, int out_size, void* d_ws, size_t ws_size,
                              hipStream_t stream) {
  const float* x  = (const float*)d_in[0];
  const float* g1 = (const float*)d_in[1];
  const float* wq = (const float*)d_in[2];
  const float* wk = (const float*)d_in[3];
  const float* wv = (const float*)d_in[4];
  const float* wo = (const float*)d_in[5];
  const float* g2 = (const float*)d_in[6];
  const float* w1 = (const float*)d_in[7];
  const float* w2 = (const float*)d_in[8];   // dict order — w2 before w3
  const float* w3 = (const float*)d_in[9];
  float* out = (float*)d_out;
  char* ws = (char*)d_ws;
  (void)in_sizes; (void)n_in; (void)out_size; (void)ws_size;

  unsigned short* Wqkv = (unsigned short*)(ws + 0);          //  3072x1024 bf16
  unsigned short* Wo   = (unsigned short*)(ws + 6291456);    //  1024x1024
  unsigned short* W13  = (unsigned short*)(ws + 8388608);    //  8192x1024
  unsigned short* W2   = (unsigned short*)(ws + 25165824);   //  1024x4096
  unsigned short* XN   = (unsigned short*)(ws + 33554432);   //  4096x1024
  unsigned short* QKV  = (unsigned short*)(ws + 41943040);   //  4096x3072
  unsigned short* OB   = (unsigned short*)(ws + 67108864);   //  4096x1024
  unsigned short* VTb  = (unsigned short*)(ws + 75497472);   //  2x1024x2048 (dead window of P13)
  unsigned short* P13  = (unsigned short*)(ws + 41943040);   //  4096x8192 (reuse; written after attn)
  float*          H    = (float*)(ws + 109051904);           //  4096x1024 fp32

  cvt_k<<<1024, 256, 0, stream>>>(wq, Wqkv,             262144);
  cvt_k<<<1024, 256, 0, stream>>>(wk, Wqkv + 1048576,   262144);
  cvt_k<<<1024, 256, 0, stream>>>(wv, Wqkv + 2097152,   262144);
  cvt_k<<<1024, 256, 0, stream>>>(wo, Wo,               262144);
  cvt_k<<<4096, 256, 0, stream>>>(w1, W13,             1048576);
  cvt_k<<<4096, 256, 0, stream>>>(w3, W13 + 4194304,   1048576);
  cvt_k<<<4096, 256, 0, stream>>>(w2, W2,              1048576);

  rmsnorm_k<<<4096, 256, 0, stream>>>(x, g1, XN);
  gemm128p<0><<<dim3(24, 32), 256, 0, stream>>>(XN, Wqkv, 1024, 1024,
                                                QKV, nullptr, nullptr, 3072, 24);
  vtrans_k<<<dim3(32, 16, 2), 256, 0, stream>>>(QKV, VTb);
  attn_k<<<dim3(16, 32), 256, 0, stream>>>(QKV, VTb, OB);
  gemm128p<1><<<dim3(8, 32), 256, 0, stream>>>(OB, Wo, 1024, 1024,
                                               nullptr, x, H, 1024, 8);
  rmsnorm_k<<<4096, 256, 0, stream>>>(H, g2, XN);
  gemm256_bt<<<dim3(32, 16), 512, 0, stream>>>(XN, W13, 1024, 1024, P13, 8192, 32);
  gate_k<<<8192, 256, 0, stream>>>(P13);
  gemm128p<1><<<dim3(8, 32), 256, 0, stream>>>(P13, W2, 4096, 8192,
                                               nullptr, H, out, 1024, 8);
}